// Round 7
// baseline (71.518 us; speedup 1.0000x reference)
//
#include <hip/hip_runtime.h>
#include <math.h>

// JacobiMachine: 1000 steps of masked 5-point Jacobi averaging on 512x512.
// Spectral method (exact): step 1 explicit, steps 2..1000 via eigen-basis
//   phi_m[i]=sin(m*pi*i/511), lam_mn=0.5*(cos(m*pi/511)+cos(n*pi/511)).
//
// Round 14: 4 kernels -> 3. k_prep is fused into k_m1 (kernel A): each block
// stages its own 18x258 gauss tile in LDS (identical expf + add order ->
// x1 values bit-identical to the old buffer), computes its 8x16 S-window
// with the same exact-reduced fp64 sin, and jc==0 blocks write the global
// S/ST tables consumed by m23/m4. Removes the prep node (+gap) and the x1
// round-trip. 3 kernels is the dataflow floor (coupling points: C1, E).
// Mirror-parity halving (R13) retained everywhere:
//   sin((511-m)pi k/511) = (-1)^(k+1) sin(m pi k/511).
// NP=64 (32 modes/corner): discarded |lam|^999 <= 3.3e-5, error < 2e-6.
// Harness floor: one 268MB re-poison fill (~41us) inside the timed region.

#define HW 512
#define NP 64
#define NC 32    // modes per corner; only pa<NC tables are stored
#define TIW 258  // gauss tile width: 256 + 2 halo

__device__ __forceinline__ int mode_of(int p) {   // p=0..63 -> {1..32} u {479..510}
    return (p < NC) ? (p + 1) : (p + 447);
}

// Kernel A = fused prep + m1.
// grid (jc=2, pg=4, iz=32) x 256 threads = 256 blocks.
// 1) stage gauss tile rows i0-1..i0+16, cols jb-1..jb+256 (clamped; clamped
//    entries are never consumed because masked x1 is 0 on the boundary)
// 2) compute S[pa0+k][i0+ii] (8x16) via exact-reduced fp64 sin; jc==0 blocks
//    also write the global S and ST tables for m23/m4
// 3) parity FMA: P[iz][pa][j] = even+odd, P[iz][63-pa][j] = odd-even
__global__ void k_a(const float* __restrict__ X, const float* __restrict__ Y,
                    float* __restrict__ S, float* __restrict__ ST,
                    float* __restrict__ P) {
    __shared__ float gT[18][TIW];
    __shared__ float sA[8][16];
    int t = threadIdx.x;
    int jb = blockIdx.x * 256;                 // 0 or 256
    int pa0 = blockIdx.y * 8;                  // 0,8,16,24
    int iz = blockIdx.z;                       // 0..31
    int i0 = iz * 16;                          // even
    // --- gauss tile (flat loop over 18*258 entries) ---
    for (int e = t; e < 18 * TIW; e += 256) {
        int r = e / TIW, c = e - r * TIW;
        int gi = i0 - 1 + r;
        int gj = jb - 1 + c;
        gi = min(max(gi, 0), HW - 1);          // clamped entries unused
        gj = min(max(gj, 0), HW - 1);
        int idx = gi * HW + gj;
        float dx = X[idx] - 0.5f, dy = Y[idx] - 0.5f;
        gT[r][c] = expf(-50.0f * (dx * dx + dy * dy));
    }
    // --- basis window (one fp64 sin per thread, t<128) ---
    if (t < 128) {
        int k = t >> 4, ii = t & 15;
        int pa = pa0 + k, i = i0 + ii;
        long tt = ((long)(pa + 1) * (long)i) % 1022;   // exact reduction
        float s = (float)sin((double)tt * (M_PI / 511.0));
        sA[k][ii] = s;
        if (blockIdx.x == 0) {                 // one writer set for the tables
            S[pa * HW + i] = s;
            ST[i * NC + pa] = s;
        }
    }
    __syncthreads();
    // --- parity FMA over the 16-i chunk ---
    int j = jb + t;
    bool jin = (j > 0) && (j < HW - 1);
    float ae[8] = {0.f, 0.f, 0.f, 0.f, 0.f, 0.f, 0.f, 0.f};
    float ao[8] = {0.f, 0.f, 0.f, 0.f, 0.f, 0.f, 0.f, 0.f};
    #pragma unroll
    for (int ii = 0; ii < 16; ii++) {
        int i = i0 + ii;
        float xv = 0.0f;
        if (jin && i > 0 && i < HW - 1) {
            // same order as the old prep: up + down + left + right
            xv = 0.25f * (gT[ii][t + 1] + gT[ii + 2][t + 1] +
                          gT[ii + 1][t] + gT[ii + 1][t + 2]);
        }
        if ((ii & 1) == 0) {
            #pragma unroll
            for (int k = 0; k < 8; k++) ae[k] += sA[k][ii] * xv;
        } else {
            #pragma unroll
            for (int k = 0; k < 8; k++) ao[k] += sA[k][ii] * xv;
        }
    }
    float* Pp = P + iz * NP * HW + j;
    #pragma unroll
    for (int k = 0; k < 8; k++) {
        Pp[(pa0 + k) * HW]      = ae[k] + ao[k];   // row pa
        Pp[(63 - pa0 - k) * HW] = ao[k] - ae[k];   // mirror row 63-pa
    }
}

// Fused m2+m3, one block per p (64 blocks x 512 threads = 8 waves):
//  load:  c1[j] = sum_{iz<32} P[iz][p][j]                    (32 coalesced, 4-way ILP)
//  ph1:   qa=t&31, jg=t>>5 (16 j-groups of 32): even/odd-j sums pe/po
//  comb:  t<32: dlo=(se+so)*L[p][qa], dhi=(so-se)*L[p][63-qa] (L inline, fp64)
//         dp[qa]=dlo+dhi (odd cols), dm[qa]=dlo-dhi (even cols)
//  ph2:   E[p][t] = sum_{qa<32} sel[qa]*S[qa,t], sel = (t&1)? dp : dm
__global__ void k_m23(const float* __restrict__ P, const float* __restrict__ ST,
                      const float* __restrict__ S, float* __restrict__ E) {
    __shared__ float c1[HW];
    __shared__ float pe[512], po[512];
    __shared__ float dp[NC], dm[NC];
    int p = blockIdx.x, t = threadIdx.x;
    // sum the 32 m1 partials for row p
    {
        const float* Pp = P + p * HW + t;
        float s0 = 0.f, s1 = 0.f, s2 = 0.f, s3 = 0.f;
        #pragma unroll
        for (int iz = 0; iz < 32; iz += 4) {
            s0 += Pp[(iz + 0) * NP * HW];
            s1 += Pp[(iz + 1) * NP * HW];
            s2 += Pp[(iz + 2) * NP * HW];
            s3 += Pp[(iz + 3) * NP * HW];
        }
        c1[t] = (s0 + s1) + (s2 + s3);
    }
    __syncthreads();
    // phase 1: 16 j-groups of 32; LDS c1 reads are 2-address broadcasts
    int qa = t & 31, jg = t >> 5;
    {
        const float* STp = ST + (jg * 32) * NC + qa;   // 128B coalesced per half-wave
        const float* cc = c1 + jg * 32;
        float be = 0.f, bo = 0.f;
        #pragma unroll
        for (int jj = 0; jj < 32; jj += 2) {
            be += cc[jj] * STp[jj * NC];
            bo += cc[jj + 1] * STp[(jj + 1) * NC];
        }
        pe[t] = be;
        po[t] = bo;
    }
    __syncthreads();
    if (t < NC) {
        float se = 0.f, so = 0.f;
        #pragma unroll
        for (int g = 0; g < 16; g++) {
            se += pe[g * 32 + t];
            so += po[g * 32 + t];
        }
        float dlo = se + so;                   // D row-term for q = t
        float dhi = so - se;                   // for q = 63 - t
        // L[p][t], L[p][63-t] inline: lam^999*(2/511)^2, binary exponentiation
        double lp = cos((double)mode_of(p) * M_PI / 511.0);
        double ca = cos((double)(t + 1) * M_PI / 511.0);   // mode_of(t)=t+1 (t<32)
        double lam1 = 0.5 * (lp + ca);                     // q = t
        double lam2 = 0.5 * (lp - ca);                     // q = 63-t (mode 510-t)
        double r1 = 1.0, b1 = fabs(lam1);
        double r2 = 1.0, b2 = fabs(lam2);
        int e = 999;                                       // 0b1111100111
        #pragma unroll
        for (int k = 0; k < 10; k++) {
            if (e & 1) { r1 *= b1; r2 *= b2; }
            b1 *= b1; b2 *= b2;
            e >>= 1;
        }
        if (lam1 < 0.0) r1 = -r1;                          // 999 odd
        if (lam2 < 0.0) r2 = -r2;
        const double sc = (2.0 / 511.0) * (2.0 / 511.0);
        dlo *= (float)(r1 * sc);
        dhi *= (float)(r2 * sc);
        dp[t] = dlo + dhi;                                 // for odd columns
        dm[t] = dlo - dhi;                                 // for even columns
    }
    __syncthreads();
    // phase 2: 32 iterations; S rows <32 only, coalesced; sel reads broadcast
    const float* sel = (t & 1) ? dp : dm;
    float e0 = 0.f, e1 = 0.f;
    #pragma unroll
    for (int q2 = 0; q2 < NC; q2 += 2) {
        e0 += sel[q2] * S[q2 * HW + t];
        e1 += sel[q2 + 1] * S[(q2 + 1) * HW + t];
    }
    E[p * HW + t] = e0 + e1;
}

// out[i][j] = sum_p S[p,i]*E[p,j]; parity trick over mirror pairs (pa, 63-pa):
// ep/em = E[pa]+-E[63-pa]; even rows i use em, odd rows ep.
// grid (jc=2, ig=128) x 256 = 256 blocks, 4 i-rows/block (i0 even).
// Boundary exact 0 via S[pa][0]=S[pa][511]=0.
__global__ void k_m4(const float* __restrict__ S, const float* __restrict__ E,
                     float* __restrict__ out) {
    int j = blockIdx.x * 256 + threadIdx.x;
    int i0 = blockIdx.y * 4;
    float a0 = 0.f, a1 = 0.f, a2 = 0.f, a3 = 0.f;
    #pragma unroll 8
    for (int pa = 0; pa < NC; pa++) {
        float elo = E[pa * HW + j];            // coalesced
        float ehi = E[(63 - pa) * HW + j];     // coalesced
        float ep = elo + ehi, em = elo - ehi;
        const float* Sp = S + pa * HW + i0;    // wave-uniform -> scalar
        a0 += Sp[0] * em;                      // i0   even
        a1 += Sp[1] * ep;                      // i0+1 odd
        a2 += Sp[2] * em;                      // i0+2 even
        a3 += Sp[3] * ep;                      // i0+3 odd
    }
    out[(i0 + 0) * HW + j] = a0;
    out[(i0 + 1) * HW + j] = a1;
    out[(i0 + 2) * HW + j] = a2;
    out[(i0 + 3) * HW + j] = a3;
}

// ---------------- launcher ----------------

extern "C" void kernel_launch(void* const* d_in, const int* in_sizes, int n_in,
                              void* d_out, int out_size, void* d_ws, size_t ws_size,
                              hipStream_t stream) {
    const float* X = (const float*)d_in[0];
    const float* Y = (const float*)d_in[1];
    float* out = (float*)d_out;

    float* ws = (float*)d_ws;
    float* S  = ws;                       // 32*512
    float* ST = S + NC * HW;              // 512*32
    float* E  = ST + HW * NC;             // 64*512
    float* P  = E + NP * HW;              // 32*64*512 (kernel A partials)

    k_a   <<<dim3(2, 4, 32),    dim3(256), 0, stream>>>(X, Y, S, ST, P);
    k_m23 <<<dim3(NP),          dim3(512), 0, stream>>>(P, ST, S, E);
    k_m4  <<<dim3(2, 128),      dim3(256), 0, stream>>>(S, E, out);
}

// Round 9
// 70.680 us; speedup vs baseline: 1.0119x; 1.0119x over previous
//
#include <hip/hip_runtime.h>
#include <math.h>

// JacobiMachine: 1000 steps of masked 5-point Jacobi averaging on 512x512.
// Spectral method (exact): step 1 explicit, steps 2..1000 via eigen-basis
//   phi_m[i]=sin(m*pi*i/511), lam_mn=0.5*(cos(m*pi/511)+cos(n*pi/511)).
//
// Round 16: resubmit of the Round-13 structure (best measured: 70.52us).
// R15 failed with "MI355X container failed twice" -- broker/infra error,
// no kernel result; source is byte-equivalent to the R13 pass. Design:
//  - mirror-parity halving everywhere: sin((511-m)pi k/511)=(-1)^(k+1)sin(m pi k/511)
//    m1: even/odd-i sums -> C1[pa]=ae+ao, C1[63-pa]=ao-ae (FMA + S reads /2)
//    m23 ph1: even/odd-j sums -> part pairs; ph2: 32-iter with dp/dm select
//    m4: ep/em = E[pa]+-E[63-pa]; even rows use em, odd rows ep
//  - NP=64 (32 modes/corner): discarded |lam|^999 <= 3.3e-5, error < 2e-6
//  - L inline in m23 (binary exponentiation, fp64), no atomics anywhere
// Harness floor ~70us: 268MB re-poison fills at ~41us/82% HBM in rocprof;
// kernels+gaps ~5-8us. Within ~1us of floor == noise band -> roofline next.

#define HW 512
#define NP 64
#define NC 32   // modes per corner; only pa<NC tables are stored

__device__ __forceinline__ int mode_of(int p) {   // p=0..63 -> {1..32} u {479..510}
    return (p < NC) ? (p + 1) : (p + 447);
}

__device__ __forceinline__ float gauss(const float* __restrict__ X,
                                       const float* __restrict__ Y, int idx) {
    float dx = X[idx] - 0.5f, dy = Y[idx] - 0.5f;
    return expf(-50.0f * (dx * dx + dy * dy));
}

// Block ranges:
//  [0,1024)    x1[idx] = masked 5-pt avg of gaussian (== one reference step)
//  [1024,1088) S[pa][i] (32 x 512) and ST[i][pa] (512 x 32), pa<32 only
__global__ void k_prep(const float* __restrict__ X, const float* __restrict__ Y,
                       float* __restrict__ x1, float* __restrict__ S,
                       float* __restrict__ ST) {
    int b = blockIdx.x, t = threadIdx.x;
    if (b < 1024) {
        int idx = b * 256 + t;
        int i = idx >> 9, j = idx & 511;
        float v = 0.0f;
        if (i > 0 && i < HW - 1 && j > 0 && j < HW - 1) {
            v = 0.25f * (gauss(X, Y, idx - HW) + gauss(X, Y, idx + HW) +
                         gauss(X, Y, idx - 1)  + gauss(X, Y, idx + 1));
        }
        x1[idx] = v;
    } else {
        int idx = (b - 1024) * 256 + t;              // 32 rows x 512 = 16384
        int pa = idx >> 9, i = idx & 511;            // pa in [0,32), m = pa+1
        long tt = ((long)(pa + 1) * (long)i) % 1022; // exact reduction
        float s = (float)sin((double)tt * (M_PI / 511.0));
        S[pa * HW + i] = s;
        ST[i * NC + pa] = s;
    }
}

// P[iz][row][j] partial of C1[row][j] = sum_i S-basis * x1[i,j]; parity trick:
// rows pa0..pa0+7 AND mirrors 63-pa from the same multiplies.
// grid (jc=2, pg=4, ic=32) x 256 = 256 blocks, 16-i chunks:
// per thread 16 x1 loads, 128 FMA, 16 stores; S reads wave-uniform scalars.
__global__ void k_m1(const float* __restrict__ S, const float* __restrict__ x1,
                     float* __restrict__ P) {
    int j = blockIdx.x * 256 + threadIdx.x;
    int pa0 = blockIdx.y * 8;                  // 0,8,16,24
    int iz = blockIdx.z;                       // 0..31
    int i0 = iz * 16;                          // even
    const float* Sb = S + pa0 * HW + i0;       // wave-uniform -> scalar loads
    const float* xp = x1 + i0 * HW + j;        // coalesced, L2-resident
    float ae[8] = {0.f, 0.f, 0.f, 0.f, 0.f, 0.f, 0.f, 0.f};
    float ao[8] = {0.f, 0.f, 0.f, 0.f, 0.f, 0.f, 0.f, 0.f};
    #pragma unroll
    for (int i = 0; i < 16; i++) {
        float x = xp[i * HW];
        if ((i & 1) == 0) {
            #pragma unroll
            for (int k = 0; k < 8; k++) ae[k] += Sb[k * HW + i] * x;
        } else {
            #pragma unroll
            for (int k = 0; k < 8; k++) ao[k] += Sb[k * HW + i] * x;
        }
    }
    float* Pp = P + iz * NP * HW + j;
    #pragma unroll
    for (int k = 0; k < 8; k++) {
        Pp[(pa0 + k) * HW]      = ae[k] + ao[k];   // row pa
        Pp[(63 - pa0 - k) * HW] = ao[k] - ae[k];   // mirror row 63-pa
    }
}

// Fused m2+m3, one block per p (64 blocks x 512 threads = 8 waves):
//  load:  c1[j] = sum_{iz<32} P[iz][p][j]                    (32 coalesced, 4-way ILP)
//  ph1:   qa=t&31, jg=t>>5 (16 j-groups of 32): even/odd-j sums pe/po
//  comb:  t<32: dlo=(se+so)*L[p][qa], dhi=(so-se)*L[p][63-qa] (L inline, fp64)
//         dp[qa]=dlo+dhi (odd cols), dm[qa]=dlo-dhi (even cols)
//  ph2:   E[p][t] = sum_{qa<32} sel[qa]*S[qa,t], sel = (t&1)? dp : dm
__global__ void k_m23(const float* __restrict__ P, const float* __restrict__ ST,
                      const float* __restrict__ S, float* __restrict__ E) {
    __shared__ float c1[HW];
    __shared__ float pe[512], po[512];
    __shared__ float dp[NC], dm[NC];
    int p = blockIdx.x, t = threadIdx.x;
    // sum the 32 m1 partials for row p
    {
        const float* Pp = P + p * HW + t;
        float s0 = 0.f, s1 = 0.f, s2 = 0.f, s3 = 0.f;
        #pragma unroll
        for (int iz = 0; iz < 32; iz += 4) {
            s0 += Pp[(iz + 0) * NP * HW];
            s1 += Pp[(iz + 1) * NP * HW];
            s2 += Pp[(iz + 2) * NP * HW];
            s3 += Pp[(iz + 3) * NP * HW];
        }
        c1[t] = (s0 + s1) + (s2 + s3);
    }
    __syncthreads();
    // phase 1: 16 j-groups of 32; LDS c1 reads are 2-address broadcasts
    int qa = t & 31, jg = t >> 5;
    {
        const float* STp = ST + (jg * 32) * NC + qa;   // 128B coalesced per half-wave
        const float* cc = c1 + jg * 32;
        float be = 0.f, bo = 0.f;
        #pragma unroll
        for (int jj = 0; jj < 32; jj += 2) {
            be += cc[jj] * STp[jj * NC];
            bo += cc[jj + 1] * STp[(jj + 1) * NC];
        }
        pe[t] = be;
        po[t] = bo;
    }
    __syncthreads();
    if (t < NC) {
        float se = 0.f, so = 0.f;
        #pragma unroll
        for (int g = 0; g < 16; g++) {
            se += pe[g * 32 + t];
            so += po[g * 32 + t];
        }
        float dlo = se + so;                   // D row-term for q = t
        float dhi = so - se;                   // for q = 63 - t
        // L[p][t], L[p][63-t] inline: lam^999*(2/511)^2, binary exponentiation
        double lp = cos((double)mode_of(p) * M_PI / 511.0);
        double ca = cos((double)(t + 1) * M_PI / 511.0);   // mode_of(t)=t+1 (t<32)
        double lam1 = 0.5 * (lp + ca);                     // q = t
        double lam2 = 0.5 * (lp - ca);                     // q = 63-t (mode 510-t)
        double r1 = 1.0, b1 = fabs(lam1);
        double r2 = 1.0, b2 = fabs(lam2);
        int e = 999;                                       // 0b1111100111
        #pragma unroll
        for (int k = 0; k < 10; k++) {
            if (e & 1) { r1 *= b1; r2 *= b2; }
            b1 *= b1; b2 *= b2;
            e >>= 1;
        }
        if (lam1 < 0.0) r1 = -r1;                          // 999 odd
        if (lam2 < 0.0) r2 = -r2;
        const double sc = (2.0 / 511.0) * (2.0 / 511.0);
        dlo *= (float)(r1 * sc);
        dhi *= (float)(r2 * sc);
        dp[t] = dlo + dhi;                                 // for odd columns
        dm[t] = dlo - dhi;                                 // for even columns
    }
    __syncthreads();
    // phase 2: 32 iterations; S rows <32 only, coalesced; sel reads broadcast
    const float* sel = (t & 1) ? dp : dm;
    float e0 = 0.f, e1 = 0.f;
    #pragma unroll
    for (int q2 = 0; q2 < NC; q2 += 2) {
        e0 += sel[q2] * S[q2 * HW + t];
        e1 += sel[q2 + 1] * S[(q2 + 1) * HW + t];
    }
    E[p * HW + t] = e0 + e1;
}

// out[i][j] = sum_p S[p,i]*E[p,j]; parity trick over mirror pairs (pa, 63-pa):
// ep/em = E[pa]+-E[63-pa]; even rows i use em, odd rows ep.
// grid (jc=2, ig=128) x 256 = 256 blocks, 4 i-rows/block (i0 even).
// Boundary exact 0 via S[pa][0]=S[pa][511]=0.
__global__ void k_m4(const float* __restrict__ S, const float* __restrict__ E,
                     float* __restrict__ out) {
    int j = blockIdx.x * 256 + threadIdx.x;
    int i0 = blockIdx.y * 4;
    float a0 = 0.f, a1 = 0.f, a2 = 0.f, a3 = 0.f;
    #pragma unroll 8
    for (int pa = 0; pa < NC; pa++) {
        float elo = E[pa * HW + j];            // coalesced
        float ehi = E[(63 - pa) * HW + j];     // coalesced
        float ep = elo + ehi, em = elo - ehi;
        const float* Sp = S + pa * HW + i0;    // wave-uniform -> scalar
        a0 += Sp[0] * em;                      // i0   even
        a1 += Sp[1] * ep;                      // i0+1 odd
        a2 += Sp[2] * em;                      // i0+2 even
        a3 += Sp[3] * ep;                      // i0+3 odd
    }
    out[(i0 + 0) * HW + j] = a0;
    out[(i0 + 1) * HW + j] = a1;
    out[(i0 + 2) * HW + j] = a2;
    out[(i0 + 3) * HW + j] = a3;
}

// ---------------- launcher ----------------

extern "C" void kernel_launch(void* const* d_in, const int* in_sizes, int n_in,
                              void* d_out, int out_size, void* d_ws, size_t ws_size,
                              hipStream_t stream) {
    const float* X = (const float*)d_in[0];
    const float* Y = (const float*)d_in[1];
    float* out = (float*)d_out;

    float* ws = (float*)d_ws;
    float* x1 = ws;                       // 512*512
    float* S  = x1 + HW * HW;             // 32*512
    float* ST = S + NC * HW;              // 512*32
    float* E  = ST + HW * NC;             // 64*512
    float* P  = E + NP * HW;              // 32*64*512 (m1 partials)

    k_prep<<<dim3(1088),        dim3(256), 0, stream>>>(X, Y, x1, S, ST);
    k_m1  <<<dim3(2, 4, 32),    dim3(256), 0, stream>>>(S, x1, P);
    k_m23 <<<dim3(NP),          dim3(512), 0, stream>>>(P, ST, S, E);
    k_m4  <<<dim3(2, 128),      dim3(256), 0, stream>>>(S, E, out);
}